// Round 1
// 268.916 us; speedup vs baseline: 1.0409x; 1.0409x over previous
//
#include <hip/hip_runtime.h>
#include <hip/hip_bf16.h>

typedef __bf16 v4bf __attribute__((ext_vector_type(4)));
typedef __bf16 v8bf __attribute__((ext_vector_type(8)));
typedef float  v16f __attribute__((ext_vector_type(16)));

#define LOG2E 1.44269504088896340736f

// round-to-nearest-even float -> bf16 bits
__device__ __forceinline__ unsigned short f2bf(float f) {
    union { float f; unsigned int u; } a; a.f = f;
    unsigned int r = a.u + 0x7FFFu + ((a.u >> 16) & 1u);
    return (unsigned short)(r >> 16);
}

__device__ __forceinline__ void unpack8(uint4 rawv, float* f) {
    unsigned int w[4] = { rawv.x, rawv.y, rawv.z, rawv.w };
    #pragma unroll
    for (int i = 0; i < 4; ++i) {
        f[2 * i]     = __uint_as_float(w[i] << 16);
        f[2 * i + 1] = __uint_as_float(w[i] & 0xFFFF0000u);
    }
}

// ---------------- Phase 0: pack W^T bf16 + zero deg (fused) ----------------
// k & q weights pre-scaled by log2(e); k additionally NEGATED so the
// gather kernel reads nk = -k' directly (sigmoid = rcp(1 + 2^(nk - q'))).
__global__ __launch_bounds__(256) void prep_w_zero(
    const float* __restrict__ Wk, const float* __restrict__ Wq,
    const float* __restrict__ Wv, const float* __restrict__ Ws,
    unsigned short* __restrict__ Wt, int* __restrict__ deg, int N)
{
    int i = blockIdx.x * 256 + threadIdx.x;      // 512 blocks -> 131072 threads
    if (i < 65536) {
        int m = i >> 14;
        int r = i & 16383;
        int n = r >> 7, k = r & 127;
        const float* W = (m == 0) ? Wk : (m == 1) ? Wq : (m == 2) ? Wv : Ws;
        float scale = (m == 0) ? -LOG2E : (m == 1) ? LOG2E : 1.0f;
        Wt[i] = f2bf(W[k * 128 + n] * scale);
    }
    if (i < N) deg[i] = 0;
}

// ---------------- Phase 1: fused MFMA GEMM, x read once ----------------
// 1024 threads = 16 waves = 16 (mat, col-tile) combos. B-frags register-
// resident; grid-stride over 32-row x-tiles staged in LDS (bf16, stride
// 132 -> 2-way bank alias = free); next tile prefetched into registers.
// q and v written INTERLEAVED: qv[node] = [q' 128 | v 128] (bf16).
// kws holds -k' (negated in weight prep).
__global__ __launch_bounds__(1024, 4) void gemm_fused(
    const float* __restrict__ x, int N,
    const unsigned short* __restrict__ Wt,
    const float* __restrict__ bk, const float* __restrict__ bq,
    const float* __restrict__ bv, const float* __restrict__ bs,
    unsigned short* __restrict__ kws, unsigned short* __restrict__ qv,
    float* __restrict__ out)
{
    __shared__ __align__(16) unsigned short xs[32 * 132];
    const int t   = threadIdx.x;
    const int wid = t >> 6;          // 0..15
    const int m   = wid >> 2;        // matrix
    const int ct  = wid & 3;         // col tile
    const int l   = t & 63;
    const int col = ct * 32 + (l & 31);
    const int kb  = (l >> 5) * 8;

    // B fragments, loaded once (L2-resident after first blocks)
    v8bf b[8];
    {
        const unsigned short* wp = Wt + m * 16384 + col * 128 + kb;
        #pragma unroll
        for (int c = 0; c < 8; ++c) b[c] = *(const v8bf*)(wp + c * 16);
    }
    const float* bvec = (m == 0) ? bk : (m == 1) ? bq : (m == 2) ? bv : bs;
    const float bcol = bvec[col] * ((m == 0) ? -LOG2E : (m == 1) ? LOG2E : 1.0f);
    unsigned short* dst; int dstride;
    if (m == 0)      { dst = kws;      dstride = 128; }
    else if (m == 1) { dst = qv;       dstride = 256; }
    else             { dst = qv + 128; dstride = 256; }   // m==2 (v half)

    // staging: thread owns one float4 of the 32x128 tile
    const int srow = t >> 5;         // 0..31
    const int sk4  = (t & 31) << 2;  // 0..124
    const int rowb = 4 * (l >> 5);

    const int ntiles = (N + 31) >> 5;
    int tile = blockIdx.x;
    if (tile >= ntiles) return;

    float4 stg = make_float4(0.f, 0.f, 0.f, 0.f);
    {
        int gr = tile * 32 + srow;
        if (gr < N) stg = *(const float4*)(x + (size_t)gr * 128 + sk4);
    }

    const unsigned short* ap = xs + (l & 31) * 132 + kb;

    while (true) {
        // write staged tile to LDS as bf16
        ushort4 pk;
        pk.x = f2bf(stg.x); pk.y = f2bf(stg.y);
        pk.z = f2bf(stg.z); pk.w = f2bf(stg.w);
        *(ushort4*)(xs + srow * 132 + sk4) = pk;
        __syncthreads();

        // prefetch next tile while computing this one
        int next = tile + gridDim.x;
        if (next < ntiles) {
            int gr = next * 32 + srow;
            stg = (gr < N) ? *(const float4*)(x + (size_t)gr * 128 + sk4)
                           : make_float4(0.f, 0.f, 0.f, 0.f);
        }

        // fused LDS-read + MFMA chain (a-frags transient: low VGPR)
        v16f acc = {};
        #pragma unroll
        for (int c = 0; c < 8; ++c) {
            v4bf a0 = *(const v4bf*)(ap + c * 16);
            v4bf a1 = *(const v4bf*)(ap + c * 16 + 4);
            v8bf a = __builtin_shufflevector(a0, a1, 0, 1, 2, 3, 4, 5, 6, 7);
            acc = __builtin_amdgcn_mfma_f32_32x32x16_bf16(a, b[c], acc, 0, 0, 0);
        }

        // C/D: col = lane&31, row = (reg&3) + 8*(reg>>2) + 4*(lane>>5)
        const int r0 = tile * 32 + rowb;
        if (m == 3) {
            #pragma unroll
            for (int reg = 0; reg < 16; ++reg) {
                int row = r0 + (reg & 3) + 8 * (reg >> 2);
                if (row < N) out[(size_t)row * 128 + col] = acc[reg] + bcol;
            }
        } else {
            #pragma unroll
            for (int reg = 0; reg < 16; ++reg) {
                int row = r0 + (reg & 3) + 8 * (reg >> 2);
                if (row < N) dst[(size_t)row * dstride + col] = f2bf(acc[reg] + bcol);
            }
        }

        tile = next;
        if (tile >= ntiles) break;
        __syncthreads();   // all A-frag reads done before next staging write
    }
}

// ---------------- Phase 2: device-built CSR (single-atomic counting sort) ----------------
// count_pos: one atomic per edge, capturing BOTH the count and the edge's
// slot within its destination row. fill_csr is then atomic-free.

__global__ __launch_bounds__(256) void count_pos(
    const int* __restrict__ ei, int E, int* __restrict__ deg,
    int* __restrict__ pos)
{
    int e = blockIdx.x * 256 + threadIdx.x;
    if (e >= E) return;
    pos[e] = atomicAdd(&deg[ei[E + e]], 1);   // dst
}

__global__ __launch_bounds__(256) void scan_chunks(
    const int* __restrict__ deg, int N, int* __restrict__ rowStart,
    int* __restrict__ chunkTot)
{
    __shared__ int sums[256];
    const int t = threadIdx.x;
    const int base = blockIdx.x * 1024 + t * 4;
    int d0 = 0, d1 = 0, d2 = 0, d3 = 0;
    if (base + 3 < N) {
        int4 dd = *(const int4*)(deg + base);
        d0 = dd.x; d1 = dd.y; d2 = dd.z; d3 = dd.w;
    } else {
        if (base + 0 < N) d0 = deg[base + 0];
        if (base + 1 < N) d1 = deg[base + 1];
        if (base + 2 < N) d2 = deg[base + 2];
        if (base + 3 < N) d3 = deg[base + 3];
    }
    int tot = d0 + d1 + d2 + d3;
    sums[t] = tot;
    __syncthreads();
    #pragma unroll
    for (int off = 1; off < 256; off <<= 1) {
        int v = (t >= off) ? sums[t - off] : 0;
        __syncthreads();
        sums[t] += v;
        __syncthreads();
    }
    int excl = sums[t] - tot;
    if (base + 0 < N) rowStart[base + 0] = excl;
    if (base + 1 < N) rowStart[base + 1] = excl + d0;
    if (base + 2 < N) rowStart[base + 2] = excl + d0 + d1;
    if (base + 3 < N) rowStart[base + 3] = excl + d0 + d1 + d2;
    if (t == 255) chunkTot[blockIdx.x] = sums[255];
}

// add chunk offsets; each block re-scans the (<=128) chunk totals in LDS
__global__ __launch_bounds__(256) void add_offsets(
    int* __restrict__ rowStart, const int* __restrict__ chunkTot,
    int N, int nChunks)
{
    __shared__ int s[128];
    const int t = threadIdx.x;
    if (t < 128) s[t] = (t < nChunks) ? chunkTot[t] : 0;
    __syncthreads();
    #pragma unroll
    for (int off = 1; off < 128; off <<= 1) {
        int u = 0;
        if (t < 128 && t >= off) u = s[t - off];
        __syncthreads();
        if (t < 128) s[t] += u;
        __syncthreads();
    }
    const int coff = (blockIdx.x == 0) ? 0 : s[blockIdx.x - 1];
    const int base = blockIdx.x * 1024 + t * 4;
    if (base + 3 < N) {
        int4 r = *(const int4*)(rowStart + base);
        r.x += coff; r.y += coff; r.z += coff; r.w += coff;
        *(int4*)(rowStart + base) = r;
    } else {
        #pragma unroll
        for (int j = 0; j < 4; ++j) {
            if (base + j < N) rowStart[base + j] += coff;
        }
    }
}

__global__ __launch_bounds__(256) void fill_csr(
    const int* __restrict__ ei, int E,
    const int* __restrict__ rowStart, const int* __restrict__ pos,
    int* __restrict__ elist)
{
    int e = blockIdx.x * 256 + threadIdx.x;
    if (e >= E) return;
    int s = ei[e];
    int d = ei[E + e];
    elist[rowStart[d] + pos[e]] = s;   // atomic-free scatter
}

// ---------------- Phase 3: owner-computes aggregation (no atomics) ----------------
// 4 nodes/wave (16 lanes each), lane owns 8 feats; q|v interleaved rows.
// Single predicated 8-edge-chunk loop: 16 gather loads in flight per
// iteration, no serial remainder. Invalid slots clamp the elist index
// (stays in-bounds) and zero the v words, contributing exactly 0.
// out RMW read + kws read hoisted to the top so they overlap the loop.
__global__ __launch_bounds__(256, 4) void gather_agg(
    const int* __restrict__ rowStart, const int* __restrict__ deg,
    const int* __restrict__ elist,
    const unsigned short* __restrict__ kws,
    const unsigned short* __restrict__ qv,
    float* __restrict__ out, int N)
{
    int gid = blockIdx.x * 256 + threadIdx.x;
    int node = gid >> 4;
    if (node >= N) return;
    int fo = (gid & 15) << 3;   // 8 feats per lane

    // issue long-latency independent loads first
    float* orow = out + (size_t)node * 128 + fo;
    float4 o0 = *(const float4*)(orow);
    float4 o1 = *(const float4*)(orow + 4);
    uint4 kraw = *(const uint4*)(kws + (size_t)node * 128 + fo);  // holds -k'
    const int p0 = rowStart[node];
    const int dg = deg[node];

    float nkf[8];
    unpack8(kraw, nkf);
    float acc[8] = {};

    const unsigned short* qvb = qv + fo;
    const int e = p0 + dg;

    for (int base = p0; base < e; base += 8) {
        int idx[8];
        #pragma unroll
        for (int s = 0; s < 8; ++s) {
            int pp = base + s;
            idx[s] = elist[pp < e ? pp : e - 1];   // clamped: always in-bounds
        }
        uint4 qr[8], vr[8];
        #pragma unroll
        for (int s = 0; s < 8; ++s) {
            const unsigned short* r = qvb + (idx[s] << 8);   // 32-bit offset
            qr[s] = *(const uint4*)(r);
            vr[s] = *(const uint4*)(r + 128);
        }
        #pragma unroll
        for (int s = 0; s < 8; ++s) {
            if (base + s >= e) {                    // predicate: zero message
                vr[s].x = 0u; vr[s].y = 0u; vr[s].z = 0u; vr[s].w = 0u;
            }
            float qf[8], vf[8];
            unpack8(qr[s], qf);
            unpack8(vr[s], vf);
            #pragma unroll
            for (int j = 0; j < 8; ++j) {
                float ex = __builtin_amdgcn_exp2f(nkf[j] - qf[j]);
                acc[j] = fmaf(__builtin_amdgcn_rcpf(1.0f + ex), vf[j], acc[j]);
            }
        }
    }

    o0.x += acc[0]; o0.y += acc[1]; o0.z += acc[2]; o0.w += acc[3];
    o1.x += acc[4]; o1.y += acc[5]; o1.z += acc[6]; o1.w += acc[7];
    *(float4*)(orow)     = o0;
    *(float4*)(orow + 4) = o1;
}

extern "C" void kernel_launch(void* const* d_in, const int* in_sizes, int n_in,
                              void* d_out, int out_size, void* d_ws, size_t ws_size,
                              hipStream_t stream) {
    const float* x    = (const float*)d_in[0];
    const int*   ei   = (const int*)d_in[1];
    const float* Wk   = (const float*)d_in[3];
    const float* bk   = (const float*)d_in[4];
    const float* Wq   = (const float*)d_in[5];
    const float* bq   = (const float*)d_in[6];
    const float* Wv   = (const float*)d_in[7];
    const float* bv   = (const float*)d_in[8];
    const float* Ws   = (const float*)d_in[9];
    const float* bias = (const float*)d_in[10];

    const int N = in_sizes[0] / 128;
    const int E = in_sizes[1] / 2;
    float* out = (float*)d_out;

    // workspace layout
    unsigned short* kws = (unsigned short*)d_ws;        // N*128 bf16 (-k', scaled)
    unsigned short* qv  = kws + (size_t)N * 128;        // N*256 bf16 (q'|v)
    int* deg      = (int*)(qv + (size_t)N * 256);
    int* rowStart = deg + N;
    int* chunkTot = rowStart + N;
    int* pos      = chunkTot + 128;                     // E ints (per-edge slot)
    int* elist    = pos + E;
    unsigned short* Wt = (unsigned short*)(elist + E);

    const int nChunks = (N + 1023) / 1024;

    prep_w_zero<<<512, 256, 0, stream>>>(Wk, Wq, Wv, Ws, Wt, deg, N);
    gemm_fused<<<1024, 1024, 0, stream>>>(
        x, N, Wt, bk, bq, bv, bias, kws, qv, out);

    count_pos<<<(E + 255) / 256, 256, 0, stream>>>(ei, E, deg, pos);
    scan_chunks<<<nChunks, 256, 0, stream>>>(deg, N, rowStart, chunkTot);
    add_offsets<<<nChunks, 256, 0, stream>>>(rowStart, chunkTot, N, nChunks);
    fill_csr<<<(E + 255) / 256, 256, 0, stream>>>(ei, E, rowStart, pos, elist);

    gather_agg<<<((size_t)N * 16 + 255) / 256, 256, 0, stream>>>(
        rowStart, deg, elist, kws, qv, out, N);
}